// Round 1
// 320.831 us; speedup vs baseline: 1.1926x; 1.1926x over previous
//
#include <hip/hip_runtime.h>

#define NN 50000
#define EE 800000
#define NB_FILL 3125
#define NB_PA 12500
#define NB_PB 512

typedef _Float16 half8 __attribute__((ext_vector_type(8)));
typedef float f32x4 __attribute__((ext_vector_type(4)));

__device__ __forceinline__ unsigned short f2h(float f){
  _Float16 h = (_Float16)f; unsigned short u; __builtin_memcpy(&u, &h, 2); return u;
}
__device__ __forceinline__ float h2f(unsigned short u){
  _Float16 h; __builtin_memcpy(&h, &u, 2); return (float)h;
}
// split f32 -> interleaved fp16 {hi, lo} at p (hi+lo == v to ~2^-24 rel)
__device__ __forceinline__ void split2h(float v, unsigned short* p){
  _Float16 hi = (_Float16)v;
  _Float16 lo = (_Float16)(v - (float)hi);
  __builtin_memcpy(p, &hi, 2);
  __builtin_memcpy(p+1, &lo, 2);
}
// async 16B global->LDS; LDS dest = wave-uniform base + lane*16
__device__ __forceinline__ void gl2lds16(const unsigned short* g, unsigned short* l){
  __builtin_amdgcn_global_load_lds(
    (const __attribute__((address_space(1))) unsigned int*)g,
    (__attribute__((address_space(3))) unsigned int*)l, 16, 0, 0);
}

// layout probe: 1 if edge_index is int64 (odd int32 words all zero)
__device__ __forceinline__ int detect_m(const int* eidx, int* sh){
  int t = threadIdx.x;
  if (t < 64){
    int v = eidx[2*t + 1];
    unsigned long long nz = __ballot(v != 0);
    if (t == 0) *sh = (nz == 0ULL) ? 1 : 0;
  }
  __syncthreads();
  return *sh;
}

// ---- merged prep: [fill buckets | prepA split-fp16 | prepB weights] ----
// fill: single-pass bucketed CSR (64 slots/node). cnt[i] = in-degree.
// No per-edge weight needed: norm factorizes, rows get scaled by their own
// dinv in the GEMM epilogues; agg multiplies the sum by dst's dinv.
__global__ __launch_bounds__(256) void k_prep(const int* __restrict__ eidx,
    const float* __restrict__ X, const float* __restrict__ W1,
    const float* __restrict__ Wmu, const float* __restrict__ Wls,
    int* __restrict__ cnt, int* __restrict__ bk,
    unsigned short* __restrict__ Asp, unsigned short* __restrict__ Bt1,
    unsigned short* __restrict__ Bt2){
  int b = blockIdx.x;
  if (b < NB_FILL){
    __shared__ int msh;
    int m = detect_m(eidx, &msh);
    int e = b*256 + threadIdx.x;            // 3125*256 == EE exactly
    int sv = m ? eidx[2*e]        : eidx[e];
    int d  = m ? eidx[2*(EE + e)] : eidx[EE + e];
    int p = atomicAdd(&cnt[d], 1);
    if (p < 64) bk[((size_t)d << 6) + p] = sv;
  } else if (b < NB_FILL + NB_PA){
    int gid = (b - NB_FILL)*256 + threadIdx.x;
    int r = gid >> 6, t = gid & 63;         // r < NN exactly
    float4 v = *(const float4*)(X + (size_t)r*256 + t*4);
    __attribute__((aligned(16))) unsigned short sh[8];
    split2h(v.x, sh); split2h(v.y, sh+2); split2h(v.z, sh+4); split2h(v.w, sh+6);
    *(uint4*)(Asp + (size_t)r*512 + t*8) = *(const uint4*)(sh);
  } else {
    int gid = (b - NB_FILL - NB_PA)*256 + threadIdx.x;  // < 131072
    int idx = gid & 65535;
    int n = idx & 255, k = idx >> 8;
    if (gid < 65536){
      unsigned short hq = f2h(W1[k*256 + n]);
      unsigned short* p = Bt1 + (size_t)n*512 + 2*k;
      p[0] = hq; p[1] = hq;
    } else {
      float w = (n < 128) ? Wmu[k*128 + n] : Wls[k*128 + (n - 128)];
      Bt2[(size_t)n*256 + k] = f2h(w);
    }
  }
}

// ---- 128x128 tile fp16 MFMA GEMM, async global_load_lds staging + XOR swizzle ----
// SCALE=1: epilogue multiplies each output row by rsqrt(cnt[row]+1) (= dinv[row]).
template<int KT, int SCALE>
__global__ __launch_bounds__(256) void k_gemm(const unsigned short* __restrict__ Asp,
                                              const unsigned short* __restrict__ Bt,
                                              unsigned short* __restrict__ C, int M,
                                              const int* __restrict__ cnt){
  __shared__ __align__(16) unsigned short sA[128*64];
  __shared__ __align__(16) unsigned short sB[128*64];
  const int tid  = threadIdx.x;
  const int wave = tid >> 6, lane = tid & 63;
  const int wm = wave >> 1, wn = wave & 1;
  const int quad = lane >> 4, l16 = lane & 15;
  const int tM = blockIdx.x, tN = blockIdx.y;
  const int rsub = lane >> 3;              // 0..7
  const int chs  = (lane & 7) ^ rsub;      // swizzled chunk this lane fetches

  f32x4 acc[4][4] = {};

  for (int kt = 0; kt < KT; ++kt){
    #pragma unroll
    for (int j = 0; j < 4; ++j){
      int q = wave*4 + j;                  // 0..15 (8 rows per instr)
      int r = q*8 + rsub;
      int arow = tM*128 + r; if (arow >= M) arow = M-1;
      gl2lds16(Asp + (size_t)arow*(KT*64) + kt*64 + chs*8, &sA[q*512]);
      gl2lds16(Bt  + (size_t)(tN*128 + r)*(KT*64) + kt*64 + chs*8, &sB[q*512]);
    }
    __syncthreads();
    #pragma unroll
    for (int ks = 0; ks < 2; ++ks){
      half8 af[4], bfr[4];
      #pragma unroll
      for (int t = 0; t < 4; ++t){
        int R = wm*64 + t*16 + l16;
        af[t]  = *(const half8*)(&sA[R*64 + ((ks*4 + quad) ^ (R & 7))*8]);
      }
      #pragma unroll
      for (int t = 0; t < 4; ++t){
        int R = wn*64 + t*16 + l16;
        bfr[t] = *(const half8*)(&sB[R*64 + ((ks*4 + quad) ^ (R & 7))*8]);
      }
      #pragma unroll
      for (int mt = 0; mt < 4; ++mt)
        #pragma unroll
        for (int nt = 0; nt < 4; ++nt)
          acc[mt][nt] = __builtin_amdgcn_mfma_f32_16x16x32_f16(af[mt], bfr[nt], acc[mt][nt], 0, 0, 0);
    }
    __syncthreads();
  }

  #pragma unroll
  for (int mt = 0; mt < 4; ++mt){
    #pragma unroll
    for (int r = 0; r < 4; ++r){
      int row = tM*128 + wm*64 + mt*16 + quad*4 + r;
      if (row < M){
        float sc = 1.f;
        if (SCALE) sc = rsqrtf((float)(cnt[row] + 1));
        #pragma unroll
        for (int nt = 0; nt < 4; ++nt){
          int cc = tN*128 + wn*64 + nt*16 + l16;
          C[(size_t)row*256 + cc] = f2h(acc[mt][nt][r] * sc);
        }
      }
    }
  }
}

// ---- agg layer1: unweighted fp16 gather-sum of pre-scaled rows, then
// h1' = dinv[i] * relu(dinv[i]*sum + b1)  (dinv folded in for layer-2 GEMM) ----
__global__ __launch_bounds__(256) void k_agg_relu(const unsigned short* __restrict__ feat,
    const int* __restrict__ cnt, const int* __restrict__ bkall,
    const float* __restrict__ b1, unsigned short* __restrict__ h1){
  int i = blockIdx.x*4 + (threadIdx.x >> 6);
  int lane = threadIdx.x & 63;
  int f0 = lane*4;
  int deg = cnt[i]; if (deg > 64) deg = 64;
  float di = rsqrtf((float)(deg + 1));
  const int* bk = bkall + ((size_t)i << 6);
  ushort4 hv = *(const ushort4*)(feat + (size_t)i*256 + f0);   // self (pre-scaled)
  float p0 = h2f(hv.x), p1 = h2f(hv.y), p2 = h2f(hv.z), p3 = h2f(hv.w);
  float q0=0.f,q1=0.f,q2=0.f,q3=0.f, r0=0.f,r1=0.f,r2=0.f,r3=0.f, t0=0.f,t1=0.f,t2=0.f,t3=0.f;
  int e = 0;
  for (; e + 8 <= deg; e += 8){
    int4 sa = *(const int4*)(bk + e);
    int4 sb = *(const int4*)(bk + e + 4);
    ushort4 v0 = *(const ushort4*)(feat + (size_t)sa.x*256 + f0);
    ushort4 v1 = *(const ushort4*)(feat + (size_t)sa.y*256 + f0);
    ushort4 v2 = *(const ushort4*)(feat + (size_t)sa.z*256 + f0);
    ushort4 v3 = *(const ushort4*)(feat + (size_t)sa.w*256 + f0);
    ushort4 v4 = *(const ushort4*)(feat + (size_t)sb.x*256 + f0);
    ushort4 v5 = *(const ushort4*)(feat + (size_t)sb.y*256 + f0);
    ushort4 v6 = *(const ushort4*)(feat + (size_t)sb.z*256 + f0);
    ushort4 v7 = *(const ushort4*)(feat + (size_t)sb.w*256 + f0);
    p0 += h2f(v0.x); p1 += h2f(v0.y); p2 += h2f(v0.z); p3 += h2f(v0.w);
    q0 += h2f(v1.x); q1 += h2f(v1.y); q2 += h2f(v1.z); q3 += h2f(v1.w);
    r0 += h2f(v2.x); r1 += h2f(v2.y); r2 += h2f(v2.z); r3 += h2f(v2.w);
    t0 += h2f(v3.x); t1 += h2f(v3.y); t2 += h2f(v3.z); t3 += h2f(v3.w);
    p0 += h2f(v4.x); p1 += h2f(v4.y); p2 += h2f(v4.z); p3 += h2f(v4.w);
    q0 += h2f(v5.x); q1 += h2f(v5.y); q2 += h2f(v5.z); q3 += h2f(v5.w);
    r0 += h2f(v6.x); r1 += h2f(v6.y); r2 += h2f(v6.z); r3 += h2f(v6.w);
    t0 += h2f(v7.x); t1 += h2f(v7.y); t2 += h2f(v7.z); t3 += h2f(v7.w);
  }
  if (e + 4 <= deg){
    int4 sa = *(const int4*)(bk + e);
    ushort4 v0 = *(const ushort4*)(feat + (size_t)sa.x*256 + f0);
    ushort4 v1 = *(const ushort4*)(feat + (size_t)sa.y*256 + f0);
    ushort4 v2 = *(const ushort4*)(feat + (size_t)sa.z*256 + f0);
    ushort4 v3 = *(const ushort4*)(feat + (size_t)sa.w*256 + f0);
    p0 += h2f(v0.x); p1 += h2f(v0.y); p2 += h2f(v0.z); p3 += h2f(v0.w);
    q0 += h2f(v1.x); q1 += h2f(v1.y); q2 += h2f(v1.z); q3 += h2f(v1.w);
    r0 += h2f(v2.x); r1 += h2f(v2.y); r2 += h2f(v2.z); r3 += h2f(v2.w);
    t0 += h2f(v3.x); t1 += h2f(v3.y); t2 += h2f(v3.z); t3 += h2f(v3.w);
    e += 4;
  }
  for (; e < deg; ++e){
    int s = bk[e];
    ushort4 v = *(const ushort4*)(feat + (size_t)s*256 + f0);
    p0 += h2f(v.x); p1 += h2f(v.y); p2 += h2f(v.z); p3 += h2f(v.w);
  }
  float s0 = p0+q0+r0+t0, s1 = p1+q1+r1+t1, s2 = p2+q2+r2+t2, s3 = p3+q3+r3+t3;
  float4 bb = *(const float4*)(b1 + f0);
  float u0 = fmaxf(di*s0 + bb.x, 0.f);
  float u1 = fmaxf(di*s1 + bb.y, 0.f);
  float u2 = fmaxf(di*s2 + bb.z, 0.f);
  float u3 = fmaxf(di*s3 + bb.w, 0.f);
  ushort4 o;
  o.x = f2h(di*u0); o.y = f2h(di*u1); o.z = f2h(di*u2); o.w = f2h(di*u3);
  *(ushort4*)(h1 + (size_t)i*256 + f0) = o;
}

// ---- agg layer2: unweighted gather-sum of pre-scaled z rows, ×di, +bias, f32 out ----
__global__ __launch_bounds__(256) void k_agg_out(const unsigned short* __restrict__ feat,
    const int* __restrict__ cnt, const int* __restrict__ bkall,
    const float* __restrict__ bmu, const float* __restrict__ bls, float* __restrict__ outp){
  int i = blockIdx.x*4 + (threadIdx.x >> 6);
  int lane = threadIdx.x & 63;
  int f0 = lane*4;
  int deg = cnt[i]; if (deg > 64) deg = 64;
  float di = rsqrtf((float)(deg + 1));
  const int* bk = bkall + ((size_t)i << 6);
  ushort4 hv = *(const ushort4*)(feat + (size_t)i*256 + f0);
  float p0 = h2f(hv.x), p1 = h2f(hv.y), p2 = h2f(hv.z), p3 = h2f(hv.w);
  float q0=0.f,q1=0.f,q2=0.f,q3=0.f, r0=0.f,r1=0.f,r2=0.f,r3=0.f, t0=0.f,t1=0.f,t2=0.f,t3=0.f;
  int e = 0;
  for (; e + 8 <= deg; e += 8){
    int4 sa = *(const int4*)(bk + e);
    int4 sb = *(const int4*)(bk + e + 4);
    ushort4 v0 = *(const ushort4*)(feat + (size_t)sa.x*256 + f0);
    ushort4 v1 = *(const ushort4*)(feat + (size_t)sa.y*256 + f0);
    ushort4 v2 = *(const ushort4*)(feat + (size_t)sa.z*256 + f0);
    ushort4 v3 = *(const ushort4*)(feat + (size_t)sa.w*256 + f0);
    ushort4 v4 = *(const ushort4*)(feat + (size_t)sb.x*256 + f0);
    ushort4 v5 = *(const ushort4*)(feat + (size_t)sb.y*256 + f0);
    ushort4 v6 = *(const ushort4*)(feat + (size_t)sb.z*256 + f0);
    ushort4 v7 = *(const ushort4*)(feat + (size_t)sb.w*256 + f0);
    p0 += h2f(v0.x); p1 += h2f(v0.y); p2 += h2f(v0.z); p3 += h2f(v0.w);
    q0 += h2f(v1.x); q1 += h2f(v1.y); q2 += h2f(v1.z); q3 += h2f(v1.w);
    r0 += h2f(v2.x); r1 += h2f(v2.y); r2 += h2f(v2.z); r3 += h2f(v2.w);
    t0 += h2f(v3.x); t1 += h2f(v3.y); t2 += h2f(v3.z); t3 += h2f(v3.w);
    p0 += h2f(v4.x); p1 += h2f(v4.y); p2 += h2f(v4.z); p3 += h2f(v4.w);
    q0 += h2f(v5.x); q1 += h2f(v5.y); q2 += h2f(v5.z); q3 += h2f(v5.w);
    r0 += h2f(v6.x); r1 += h2f(v6.y); r2 += h2f(v6.z); r3 += h2f(v6.w);
    t0 += h2f(v7.x); t1 += h2f(v7.y); t2 += h2f(v7.z); t3 += h2f(v7.w);
  }
  if (e + 4 <= deg){
    int4 sa = *(const int4*)(bk + e);
    ushort4 v0 = *(const ushort4*)(feat + (size_t)sa.x*256 + f0);
    ushort4 v1 = *(const ushort4*)(feat + (size_t)sa.y*256 + f0);
    ushort4 v2 = *(const ushort4*)(feat + (size_t)sa.z*256 + f0);
    ushort4 v3 = *(const ushort4*)(feat + (size_t)sa.w*256 + f0);
    p0 += h2f(v0.x); p1 += h2f(v0.y); p2 += h2f(v0.z); p3 += h2f(v0.w);
    q0 += h2f(v1.x); q1 += h2f(v1.y); q2 += h2f(v1.z); q3 += h2f(v1.w);
    r0 += h2f(v2.x); r1 += h2f(v2.y); r2 += h2f(v2.z); r3 += h2f(v2.w);
    t0 += h2f(v3.x); t1 += h2f(v3.y); t2 += h2f(v3.z); t3 += h2f(v3.w);
    e += 4;
  }
  for (; e < deg; ++e){
    int s = bk[e];
    ushort4 v = *(const ushort4*)(feat + (size_t)s*256 + f0);
    p0 += h2f(v.x); p1 += h2f(v.y); p2 += h2f(v.z); p3 += h2f(v.w);
  }
  float a0 = di*(p0+q0+r0+t0), a1 = di*(p1+q1+r1+t1);
  float a2 = di*(p2+q2+r2+t2), a3 = di*(p3+q3+r3+t3);
  float4 o;
  if (f0 < 128){
    float4 bb = *(const float4*)(bmu + f0);
    o.x = a0 + bb.x; o.y = a1 + bb.y; o.z = a2 + bb.z; o.w = a3 + bb.w;
    *(float4*)(outp + (size_t)i*128 + f0) = o;
  } else {
    int g = f0 - 128;
    float4 bb = *(const float4*)(bls + g);
    o.x = a0 + bb.x; o.y = a1 + bb.y; o.z = a2 + bb.z; o.w = a3 + bb.w;
    *(float4*)(outp + (size_t)NN*128 + (size_t)i*128 + g) = o;
  }
}

extern "C" void kernel_launch(void* const* d_in, const int* in_sizes, int n_in,
                              void* d_out, int out_size, void* d_ws, size_t ws_size,
                              hipStream_t stream){
  const float* x   = (const float*)d_in[0];
  const int* eidx  = (const int*)d_in[1];
  const float* W1  = (const float*)d_in[2];
  const float* b1  = (const float*)d_in[3];
  const float* Wmu = (const float*)d_in[4];
  const float* bmu = (const float*)d_in[5];
  const float* Wls = (const float*)d_in[6];
  const float* bls = (const float*)d_in[7];
  float* out = (float*)d_out;

  char* ws = (char*)d_ws;
  size_t off = 0;
  auto alloc = [&](size_t bytes)->char*{
    char* p = ws + off; off = (off + bytes + 511) & ~(size_t)511; return p;
  };
  int* cnt      = (int*)alloc(NN*4);
  int* buckets  = (int*)alloc((size_t)NN*64*4);
  unsigned short* Bt1 = (unsigned short*)alloc((size_t)256*512*2);
  unsigned short* Bt2 = (unsigned short*)alloc((size_t)256*256*2);
  unsigned short* AspX = (unsigned short*)alloc((size_t)NN*512*2);
  unsigned short* h1  = (unsigned short*)alloc((size_t)NN*256*2);  // fp16
  unsigned short* h   = (unsigned short*)alloc((size_t)NN*256*2);  // fp16 (reused as z)
  unsigned short* z   = h;   // h dead after k_agg_relu; reuse for z

  hipMemsetAsync(cnt, 0, NN*4, stream);
  k_prep<<<NB_FILL + NB_PA + NB_PB, 256, 0, stream>>>(eidx, x, W1, Wmu, Wls,
                                                      cnt, buckets, AspX, Bt1, Bt2);
  k_gemm<8,1><<<dim3(391, 2), 256, 0, stream>>>(AspX, Bt1, h, NN, cnt);
  k_agg_relu<<<12500, 256, 0, stream>>>(h, cnt, buckets, b1, h1);
  k_gemm<4,0><<<dim3(391, 2), 256, 0, stream>>>(h1, Bt2, z, NN, cnt);
  k_agg_out<<<12500, 256, 0, stream>>>(z, cnt, buckets, bmu, bls, out);
}